// Round 3
// baseline (750.855 us; speedup 1.0000x reference)
//
#include <hip/hip_runtime.h>
#include <hip/hip_fp16.h>
#include <stdint.h>

// Problem constants (LLaMA-7B up-proj, tokens=4096)
#define TOKENS 4096
#define OFEAT  11008
#define IFEAT  4096
#define NGRP   64            // groups per output row (IFEAT/64)
#define NGTOT  (OFEAT*NGRP)  // 704512 groups

// GEMM tiling (m97 structure: 128x128 tile, BK=32, 4 waves, 2 barriers/K-step)
#define BM 128
#define BN 128
#define BK 32
#define NT_M (TOKENS/BM)   // 32
#define NT_N (OFEAT/BN)    // 86
#define NWG  (NT_M*NT_N)   // 2752 (divisible by 8 -> simple XCD swizzle is bijective)

typedef _Float16 half8 __attribute__((ext_vector_type(8)));
typedef float    floatx4 __attribute__((ext_vector_type(4)));

#define AS1 __attribute__((address_space(1)))
#define AS3 __attribute__((address_space(3)))

__device__ __forceinline__ void gload_lds16(const void* g, void* l) {
  // async global->LDS, 16B per lane; LDS dest is wave-uniform base + lane*16,
  // global source is per-lane (m104/m108 semantics).
  __builtin_amdgcn_global_load_lds((const AS1 uint32_t*)g, (AS3 uint32_t*)l, 16, 0, 0);
}

// ---------------- pass 1: x fp32 -> f16 ----------------
__global__ __launch_bounds__(256) void cvt_x(const float* __restrict__ x,
                                             _Float16* __restrict__ xh) {
  int t = blockIdx.x * 256 + threadIdx.x;      // 2,097,152 threads, 8 elems each
  const float4* x4 = (const float4*)x;
  float4 a = x4[2*t], c = x4[2*t + 1];
  half8 h;
  h[0] = (_Float16)a.x; h[1] = (_Float16)a.y; h[2] = (_Float16)a.z; h[3] = (_Float16)a.w;
  h[4] = (_Float16)c.x; h[5] = (_Float16)c.y; h[6] = (_Float16)c.z; h[7] = (_Float16)c.w;
  *(half8*)(xh + (size_t)t * 8) = h;
}

// ---------------- pass 2: dequant packed 4-bit -> f16 W[O][I] ----------------
// packing: byte b of group = (q[b] << 4) | q[b+32];  w = q*inv_scale + mn
// 8 threads per group: s<4 -> hi nibbles of bytes [s*8, s*8+8) -> positions [s*8, +8)
//                      s>=4 -> lo nibbles of bytes [(s-4)*8, +8) -> positions [32+(s-4)*8, +8)
__global__ __launch_bounds__(256) void dequant_w(const void* __restrict__ packed,
                                                 const float* __restrict__ mn,
                                                 const float* __restrict__ inv_scale,
                                                 _Float16* __restrict__ W) {
  int t = blockIdx.x * 256 + threadIdx.x;
  int g = t >> 3;          // global group id = o*NGRP + gi
  int s = t & 7;

  // Detect storage dtype of `packed` once per block: harness may deliver the
  // reference's uint8 array widened to int32 ("integer -> const int*").
  // If int32-widened: the first 8 words are each in [0,256). If raw bytes:
  // a word is <256 only if its top 3 packed bytes are zero (each byte is
  // (q_hi<<4)|q_lo, q in 0..7) -> false-positive prob ~ (1e-6)^8, negligible.
  __shared__ int is_i32_s;
  if (threadIdx.x == 0) {
    const int* pi = (const int*)packed;
    int ok = 1;
#pragma unroll
    for (int i = 0; i < 8; ++i) ok &= ((unsigned)pi[i] < 256u);
    is_i32_s = ok;
  }
  __syncthreads();

  const int hi = (s < 4) ? 1 : 0;
  const int bbase = (s & 3) * 8;   // first packed-byte index within the group's 32 bytes
  unsigned char b[8];
  if (is_i32_s) {
    const int4* p = (const int4*)packed + ((size_t)g * 32 + bbase) / 4;
    int4 w0 = p[0], w1 = p[1];
    b[0] = (unsigned char)w0.x; b[1] = (unsigned char)w0.y;
    b[2] = (unsigned char)w0.z; b[3] = (unsigned char)w0.w;
    b[4] = (unsigned char)w1.x; b[5] = (unsigned char)w1.y;
    b[6] = (unsigned char)w1.z; b[7] = (unsigned char)w1.w;
  } else {
    const unsigned char* p8 = (const unsigned char*)packed + (size_t)g * 32 + bbase;
    uint2 w = *(const uint2*)p8;
    b[0] = w.x & 0xff; b[1] = (w.x >> 8) & 0xff; b[2] = (w.x >> 16) & 0xff; b[3] = (w.x >> 24) & 0xff;
    b[4] = w.y & 0xff; b[5] = (w.y >> 8) & 0xff; b[6] = (w.y >> 16) & 0xff; b[7] = (w.y >> 24) & 0xff;
  }

  float m  = mn[g];
  float sc = inv_scale[g];
  int shift = hi ? 4 : 0;
  half8 h;
#pragma unroll
  for (int j = 0; j < 8; ++j) {
    unsigned q = (b[j] >> shift) & 0xF;
    h[j] = (_Float16)fmaf((float)q, sc, m);
  }
  // output position: group base + (hi? s*8 : 32 + (s-4)*8)
  size_t off = (size_t)g * 64 + (hi ? 0 : 32) + (s & 3) * 8;
  *(half8*)(W + off) = h;
}

// ---------------- pass 3: GEMM C = A @ B^T + bias ----------------
// A[M=4096][K=4096] f16 row-major, B[N=11008][K=4096] f16 row-major (W layout),
// C[M][N] fp32. m97 structure: 128x128 tile, BK=32, 4 waves -> 64x64 quadrants,
// mfma_f32_16x16x32_f16, global_load_lds width-16 staging, 2 barriers/K-step.
__global__ __launch_bounds__(256) void gemm_f16(const _Float16* __restrict__ A,
                                                const _Float16* __restrict__ B,
                                                const float* __restrict__ bias,
                                                float* __restrict__ C) {
  __shared__ _Float16 sA[BM * BK];   // 8 KiB, linear [row][k] (64 B rows)
  __shared__ _Float16 sB[BN * BK];   // 8 KiB

  // bijective XCD swizzle (NWG % 8 == 0): consecutive tiles share an XCD L2
  int bid = blockIdx.x;
  int swz = (bid & 7) * (NWG >> 3) + (bid >> 3);
  int tm = swz / NT_N, tn = swz % NT_N;

  int tid  = threadIdx.x;
  int wave = tid >> 6, lane = tid & 63;
  int wr = (wave >> 1) * 64;   // wave's quadrant row origin in tile
  int wc = (wave & 1) * 64;    // quadrant col origin

  // staging map: thread tid=(w,lane) -> LDS byte w*1024+lane*16 == tid*16,
  // which equals row (tid>>2), kbyte (tid&3)*16 of the linear [row][k] tile.
  // Per-lane global source matches (row0,kb0) -> layout-consistent (m97).
  const size_t K2 = (size_t)IFEAT * 2;          // row stride in bytes
  int row0 = tid >> 2;                          // rows 0..63 (call 0), +64 (call 1)
  int kb0  = (tid & 3) << 4;                    // byte offset within the 64B k-slab
  const char* gA = (const char*)A + (size_t)(tm * BM + row0) * K2 + kb0;
  const char* gB = (const char*)B + (size_t)(tn * BN + row0) * K2 + kb0;
  char* lA = (char*)sA + wave * 1024;           // wave-uniform LDS dest
  char* lB = (char*)sB + wave * 1024;

  floatx4 acc[4][4] = {};

  // fragment read base: lane l -> row (l&15), k-chunk (l>>4)*8 (contiguous 16B)
  int lr = lane & 15;
  int lk = (lane >> 4) << 3;
  const _Float16* sAr = &sA[(wr + lr) * BK + lk];
  const _Float16* sBr = &sB[(wc + lr) * BK + lk];

  for (int kt = 0; kt < IFEAT / BK; ++kt) {
    gload_lds16(gA,           lA);
    gload_lds16(gA + 64 * K2, lA + 4096);
    gload_lds16(gB,           lB);
    gload_lds16(gB + 64 * K2, lB + 4096);
    gA += BK * 2; gB += BK * 2;
    __syncthreads();   // compiler drains vmcnt(0) before barrier -> staging visible

    half8 af[4], bf[4];
#pragma unroll
    for (int i = 0; i < 4; ++i) af[i] = *(const half8*)(sAr + i * 16 * BK);
#pragma unroll
    for (int j = 0; j < 4; ++j) bf[j] = *(const half8*)(sBr + j * 16 * BK);
#pragma unroll
    for (int i = 0; i < 4; ++i)
#pragma unroll
      for (int j = 0; j < 4; ++j)
        acc[i][j] = __builtin_amdgcn_mfma_f32_16x16x32_f16(af[i], bf[j], acc[i][j], 0, 0, 0);
    __syncthreads();   // all waves done reading before next stage overwrites
  }

  // epilogue: C/D layout col = lane&15, row = (lane>>4)*4 + reg (m89/m91)
  int lq = (lane >> 4) << 2;
#pragma unroll
  for (int j = 0; j < 4; ++j) {
    int col = tn * BN + wc + j * 16 + lr;
    float bv = bias[col];
#pragma unroll
    for (int i = 0; i < 4; ++i) {
      int row = tm * BM + wr + i * 16 + lq;
#pragma unroll
      for (int p = 0; p < 4; ++p) {
        C[(size_t)(row + p) * OFEAT + col] = acc[i][j][p] + bv;
      }
    }
  }
}

extern "C" void kernel_launch(void* const* d_in, const int* in_sizes, int n_in,
                              void* d_out, int out_size, void* d_ws, size_t ws_size,
                              hipStream_t stream) {
  const float* x         = (const float*)d_in[0];
  const void*  packed    = d_in[1];
  const float* mn        = (const float*)d_in[2];
  const float* inv_scale = (const float*)d_in[3];
  const float* bias      = (const float*)d_in[4];
  float* out = (float*)d_out;

  // workspace layout: xh (32 MiB) | wh (86 MiB)  -> needs ~118 MiB of ws
  _Float16* xh = (_Float16*)d_ws;
  _Float16* wh = (_Float16*)((char*)d_ws + (size_t)TOKENS * IFEAT * 2);

  cvt_x<<<(TOKENS * IFEAT) / (256 * 8), 256, 0, stream>>>(x, xh);
  dequant_w<<<(NGTOT * 8) / 256, 256, 0, stream>>>(packed, mn, inv_scale, wh);
  gemm_f16<<<NWG, 256, 0, stream>>>(xh, wh, bias, out);
}

// Round 4
// 648.938 us; speedup vs baseline: 1.1571x; 1.1571x over previous
//
#include <hip/hip_runtime.h>
#include <hip/hip_fp16.h>
#include <stdint.h>

// Problem constants (LLaMA-7B up-proj, tokens=4096)
#define TOKENS 4096
#define OFEAT  11008
#define IFEAT  4096
#define NGRP   64
#define NGTOT  (OFEAT*NGRP)  // 704512 groups

// GEMM tiling: 256x256 tile, BK=32, 8 waves (2Mx4N), triple-buffered LDS
#define BM 256
#define BN 256
#define BK 32
#define NT_M (TOKENS/BM)   // 16
#define NT_N (OFEAT/BN)    // 43
#define NWG  (NT_M*NT_N)   // 688 (divisible by 8 -> XCD swizzle bijective)
#define NKT  (IFEAT/BK)    // 128 K-tiles

typedef _Float16 half8 __attribute__((ext_vector_type(8)));
typedef float    floatx4 __attribute__((ext_vector_type(4)));

#define AS1 __attribute__((address_space(1)))
#define AS3 __attribute__((address_space(3)))

__device__ __forceinline__ void gload16(const void* g, void* l) {
  // async global->LDS: LDS dest = wave-uniform base + lane*16 (linear),
  // global source per-lane (m104/m108). Source carries the inverse swizzle.
  __builtin_amdgcn_global_load_lds((const AS1 uint32_t*)g, (AS3 uint32_t*)l, 16, 0, 0);
}

// ---------------- pass 1: x fp32 -> f16 ----------------
__global__ __launch_bounds__(256) void cvt_x(const float* __restrict__ x,
                                             _Float16* __restrict__ xh) {
  int t = blockIdx.x * 256 + threadIdx.x;
  const float4* x4 = (const float4*)x;
  float4 a = x4[2*t], c = x4[2*t + 1];
  half8 h;
  h[0] = (_Float16)a.x; h[1] = (_Float16)a.y; h[2] = (_Float16)a.z; h[3] = (_Float16)a.w;
  h[4] = (_Float16)c.x; h[5] = (_Float16)c.y; h[6] = (_Float16)c.z; h[7] = (_Float16)c.w;
  *(half8*)(xh + (size_t)t * 8) = h;
}

// ---------------- pass 2: dequant packed 4-bit -> f16 W[O][I] ----------------
// byte b of group = (q[b] << 4) | q[b+32];  w = q*inv_scale + mn
__global__ __launch_bounds__(256) void dequant_w(const void* __restrict__ packed,
                                                 const float* __restrict__ mn,
                                                 const float* __restrict__ inv_scale,
                                                 _Float16* __restrict__ W) {
  int t = blockIdx.x * 256 + threadIdx.x;
  int g = t >> 3;
  int s = t & 7;

  // int32-widened vs raw-uint8 detection (false-positive prob ~(1e-6)^8)
  __shared__ int is_i32_s;
  if (threadIdx.x == 0) {
    const int* pi = (const int*)packed;
    int ok = 1;
#pragma unroll
    for (int i = 0; i < 8; ++i) ok &= ((unsigned)pi[i] < 256u);
    is_i32_s = ok;
  }
  __syncthreads();

  const int hi = (s < 4) ? 1 : 0;
  const int bbase = (s & 3) * 8;
  unsigned char b[8];
  if (is_i32_s) {
    const int4* p = (const int4*)packed + ((size_t)g * 32 + bbase) / 4;
    int4 w0 = p[0], w1 = p[1];
    b[0] = (unsigned char)w0.x; b[1] = (unsigned char)w0.y;
    b[2] = (unsigned char)w0.z; b[3] = (unsigned char)w0.w;
    b[4] = (unsigned char)w1.x; b[5] = (unsigned char)w1.y;
    b[6] = (unsigned char)w1.z; b[7] = (unsigned char)w1.w;
  } else {
    const unsigned char* p8 = (const unsigned char*)packed + (size_t)g * 32 + bbase;
    uint2 w = *(const uint2*)p8;
    b[0] = w.x & 0xff; b[1] = (w.x >> 8) & 0xff; b[2] = (w.x >> 16) & 0xff; b[3] = (w.x >> 24) & 0xff;
    b[4] = w.y & 0xff; b[5] = (w.y >> 8) & 0xff; b[6] = (w.y >> 16) & 0xff; b[7] = (w.y >> 24) & 0xff;
  }

  float m  = mn[g];
  float sc = inv_scale[g];
  int shift = hi ? 4 : 0;
  half8 h;
#pragma unroll
  for (int j = 0; j < 8; ++j) {
    unsigned q = (b[j] >> shift) & 0xF;
    h[j] = (_Float16)fmaf((float)q, sc, m);
  }
  size_t off = (size_t)g * 64 + (hi ? 0 : 32) + (s & 3) * 8;
  *(half8*)(W + off) = h;
}

// ---------------- pass 3: GEMM C = A @ B^T + bias ----------------
// 256x256 tile, BK=32, 8 waves (2Mx4N, wave tile 128x64), triple-buffered
// 96KB LDS, counted vmcnt(4) pipeline (prefetch distance 2 K-tiles),
// T2 XOR swizzle (pre-swizzled source + swizzled read), T5 setprio.
//
// LDS per buffer: A 256x32 f16 (16KB, 64B rows) then B 256x32 (16KB).
// Swizzle: physical 16B-slot = logical_slot ^ ((row>>1)&3). Applied on the
// global SOURCE during staging (linear LDS dest, rule 21) and on the read.

__device__ __forceinline__ void stage_tile(const char* a, const char* b,
                                           char* lA, char* lB, size_t K2) {
  gload16(a,            lA);          // A rows   0..127 (this wave's 1KB slice)
  gload16(a + 128 * K2, lA + 8192);   // A rows 128..255
  gload16(b,            lB);
  gload16(b + 128 * K2, lB + 8192);
}

__device__ __forceinline__ void compute_tile(const _Float16* bA, const _Float16* bB,
                                             floatx4 (&acc)[8][4],
                                             int lofs, int arow, int brow) {
  half8 af[8], bf[4];
#pragma unroll
  for (int fr = 0; fr < 8; ++fr)
    af[fr] = *(const half8*)(bA + (arow + fr * 16) * 32 + lofs);
#pragma unroll
  for (int fc = 0; fc < 4; ++fc)
    bf[fc] = *(const half8*)(bB + (brow + fc * 16) * 32 + lofs);
  __builtin_amdgcn_s_setprio(1);
#pragma unroll
  for (int fr = 0; fr < 8; ++fr)
#pragma unroll
    for (int fc = 0; fc < 4; ++fc)
      acc[fr][fc] = __builtin_amdgcn_mfma_f32_16x16x32_f16(af[fr], bf[fc], acc[fr][fc], 0, 0, 0);
  __builtin_amdgcn_s_setprio(0);
}

// fused wait+barrier: single asm so no LDS op can slip between the counted
// drain and the barrier (cross-wave staging completeness needs both).
#define WAITBAR4() asm volatile("s_waitcnt vmcnt(4)\n\ts_barrier" ::: "memory")
#define WAITBAR0() asm volatile("s_waitcnt vmcnt(0)\n\ts_barrier" ::: "memory")

__global__ __launch_bounds__(512, 2) void gemm_f16(const _Float16* __restrict__ A,
                                                   const _Float16* __restrict__ B,
                                                   const float* __restrict__ bias,
                                                   float* __restrict__ C) {
  __shared__ __align__(16) _Float16 smem[3 * 16384];   // 96 KiB

  int bid = blockIdx.x;
  int swz = (bid & 7) * (NWG >> 3) + (bid >> 3);   // XCD-aware, bijective
  int tm = swz / NT_N, tn = swz % NT_N;

  int tid  = threadIdx.x;
  int wave = tid >> 6, lane = tid & 63;
  int wm = wave >> 2, wn = wave & 3;       // 2M x 4N waves, wave tile 128x64

  // --- staging addresses: thread t covers LDS bytes t*16 of each 8KB half.
  // Linear LDS (row = t>>2 [+128], slot_p = t&3); source pre-swizzled:
  // k-slot = slot_p ^ ((row>>1)&3) = (t&3) ^ ((t>>3)&3)  (half-independent).
  const size_t K2 = (size_t)IFEAT * 2;
  int kswz = (((tid & 3) ^ ((tid >> 3) & 3)) << 4);
  const char* gA = (const char*)A + (size_t)(tm * BM + (tid >> 2)) * K2 + kswz;
  const char* gB = (const char*)B + (size_t)(tn * BN + (tid >> 2)) * K2 + kswz;

  int dstoff = wave * 1024;                // wave-uniform LDS dest offset
  _Float16* A0 = smem;              _Float16* B0 = smem + 8192;
  _Float16* A1 = smem + 16384;      _Float16* B1 = smem + 24576;
  _Float16* A2 = smem + 32768;      _Float16* B2 = smem + 40960;
  char* lA0 = (char*)A0 + dstoff;  char* lB0 = (char*)B0 + dstoff;
  char* lA1 = (char*)A1 + dstoff;  char* lB1 = (char*)B1 + dstoff;
  char* lA2 = (char*)A2 + dstoff;  char* lB2 = (char*)B2 + dstoff;

  // --- fragment read offsets (swizzled): lane l, frag row base R (mult of 16):
  // row = R + (l&15), logical slot = l>>4, physical = slot ^ ((row>>1)&3);
  // since R is a multiple of 16, key reduces to ((l&15)>>1)&3.
  int x = lane & 15;
  int pslot = (lane >> 4) ^ ((x >> 1) & 3);
  int lofs = x * 32 + pslot * 8;           // in f16 units (row stride 32)
  const int arow = wm * 128;
  const int brow = wn * 64;

  floatx4 acc[8][4] = {};

  // --- prologue: stage tiles 0,1; confirm tile 0 (drain to 4) ---
  stage_tile(gA,      gB,      lA0, lB0, K2);
  stage_tile(gA + 64, gB + 64, lA1, lB1, K2);
  WAITBAR4();

  // --- main loop: 42 blocks x 3 tiles. Invariant at each body entry:
  // outstanding = next tile's 4 loads; this tile confirmed. Each body:
  // issue tile t+2 (+4), compute t, drain to 4 => t+1 confirmed.
  for (int t = 0; t < NKT - 2; t += 3) {
    const char* a = gA + (size_t)(t + 2) * 64;
    const char* b = gB + (size_t)(t + 2) * 64;
    stage_tile(a, b, lA2, lB2, K2);
    compute_tile(A0, B0, acc, lofs, arow, brow);
    WAITBAR4();

    stage_tile(a + 64, b + 64, lA0, lB0, K2);
    compute_tile(A1, B1, acc, lofs, arow, brow);
    WAITBAR4();

    stage_tile(a + 128, b + 128, lA1, lB1, K2);
    compute_tile(A2, B2, acc, lofs, arow, brow);
    WAITBAR4();
  }
  // tiles 126 (buf0) and 127 (buf1) remain; 127's loads still in flight
  compute_tile(A0, B0, acc, lofs, arow, brow);
  WAITBAR0();
  compute_tile(A1, B1, acc, lofs, arow, brow);

  // --- epilogue: C/D layout col = lane&15, row = (lane>>4)*4 + reg ---
  int rowq = (lane >> 4) << 2;
  int colbase = tn * BN + brow + x;
#pragma unroll
  for (int fc = 0; fc < 4; ++fc) {
    int col = colbase + fc * 16;
    float bv = bias[col];
#pragma unroll
    for (int fr = 0; fr < 8; ++fr) {
      int row = tm * BM + arow + fr * 16 + rowq;
#pragma unroll
      for (int p = 0; p < 4; ++p)
        C[(size_t)(row + p) * OFEAT + col] = acc[fr][fc][p] + bv;
    }
  }
}

extern "C" void kernel_launch(void* const* d_in, const int* in_sizes, int n_in,
                              void* d_out, int out_size, void* d_ws, size_t ws_size,
                              hipStream_t stream) {
  const float* x         = (const float*)d_in[0];
  const void*  packed    = d_in[1];
  const float* mn        = (const float*)d_in[2];
  const float* inv_scale = (const float*)d_in[3];
  const float* bias      = (const float*)d_in[4];
  float* out = (float*)d_out;

  _Float16* xh = (_Float16*)d_ws;
  _Float16* wh = (_Float16*)((char*)d_ws + (size_t)TOKENS * IFEAT * 2);

  cvt_x<<<(TOKENS * IFEAT) / (256 * 8), 256, 0, stream>>>(x, xh);
  dequant_w<<<(NGTOT * 8) / 256, 256, 0, stream>>>(packed, mn, inv_scale, wh);
  gemm_f16<<<NWG, 512, 0, stream>>>(xh, wh, bias, out);
}

// Round 5
// 631.805 us; speedup vs baseline: 1.1884x; 1.0271x over previous
//
#include <hip/hip_runtime.h>
#include <hip/hip_fp16.h>
#include <stdint.h>

// Problem constants (LLaMA-7B up-proj, tokens=4096)
#define TOKENS 4096
#define OFEAT  11008
#define IFEAT  4096
#define NGRP   64
#define NGTOT  (OFEAT*NGRP)  // 704512 groups

// GEMM tiling: 256x256 tile, BK=32, 8 waves (2Mx4N), triple-buffered LDS
#define BM 256
#define BN 256
#define BK 32
#define NT_M (TOKENS/BM)   // 16
#define NT_N (OFEAT/BN)    // 43
#define NWG  (NT_M*NT_N)   // 688 (divisible by 8 -> XCD swizzle bijective)
#define NKT  (IFEAT/BK)    // 128 K-tiles

typedef _Float16 half8 __attribute__((ext_vector_type(8)));
typedef float    floatx4 __attribute__((ext_vector_type(4)));

#define AS1 __attribute__((address_space(1)))
#define AS3 __attribute__((address_space(3)))

__device__ __forceinline__ void gload16(const void* g, void* l) {
  // async global->LDS: LDS dest = wave-uniform base + lane*16 (linear),
  // global source per-lane (m104/m108). Source carries the inverse swizzle.
  __builtin_amdgcn_global_load_lds((const AS1 uint32_t*)g, (AS3 uint32_t*)l, 16, 0, 0);
}

// ---------------- pass 1: x fp32 -> f16 ----------------
__global__ __launch_bounds__(256) void cvt_x(const float* __restrict__ x,
                                             _Float16* __restrict__ xh) {
  int t = blockIdx.x * 256 + threadIdx.x;
  const float4* x4 = (const float4*)x;
  float4 a = x4[2*t], c = x4[2*t + 1];
  half8 h;
  h[0] = (_Float16)a.x; h[1] = (_Float16)a.y; h[2] = (_Float16)a.z; h[3] = (_Float16)a.w;
  h[4] = (_Float16)c.x; h[5] = (_Float16)c.y; h[6] = (_Float16)c.z; h[7] = (_Float16)c.w;
  *(half8*)(xh + (size_t)t * 8) = h;
}

// ---------------- pass 2: dequant packed 4-bit -> f16 W[O][I] ----------------
// byte b of group = (q[b] << 4) | q[b+32];  w = q*inv_scale + mn
__global__ __launch_bounds__(256) void dequant_w(const void* __restrict__ packed,
                                                 const float* __restrict__ mn,
                                                 const float* __restrict__ inv_scale,
                                                 _Float16* __restrict__ W) {
  int t = blockIdx.x * 256 + threadIdx.x;
  int g = t >> 3;
  int s = t & 7;

  // int32-widened vs raw-uint8 detection (false-positive prob ~(1e-6)^8)
  __shared__ int is_i32_s;
  if (threadIdx.x == 0) {
    const int* pi = (const int*)packed;
    int ok = 1;
#pragma unroll
    for (int i = 0; i < 8; ++i) ok &= ((unsigned)pi[i] < 256u);
    is_i32_s = ok;
  }
  __syncthreads();

  const int hi = (s < 4) ? 1 : 0;
  const int bbase = (s & 3) * 8;
  unsigned char b[8];
  if (is_i32_s) {
    const int4* p = (const int4*)packed + ((size_t)g * 32 + bbase) / 4;
    int4 w0 = p[0], w1 = p[1];
    b[0] = (unsigned char)w0.x; b[1] = (unsigned char)w0.y;
    b[2] = (unsigned char)w0.z; b[3] = (unsigned char)w0.w;
    b[4] = (unsigned char)w1.x; b[5] = (unsigned char)w1.y;
    b[6] = (unsigned char)w1.z; b[7] = (unsigned char)w1.w;
  } else {
    const unsigned char* p8 = (const unsigned char*)packed + (size_t)g * 32 + bbase;
    uint2 w = *(const uint2*)p8;
    b[0] = w.x & 0xff; b[1] = (w.x >> 8) & 0xff; b[2] = (w.x >> 16) & 0xff; b[3] = (w.x >> 24) & 0xff;
    b[4] = w.y & 0xff; b[5] = (w.y >> 8) & 0xff; b[6] = (w.y >> 16) & 0xff; b[7] = (w.y >> 24) & 0xff;
  }

  float m  = mn[g];
  float sc = inv_scale[g];
  int shift = hi ? 4 : 0;
  half8 h;
#pragma unroll
  for (int j = 0; j < 8; ++j) {
    unsigned q = (b[j] >> shift) & 0xF;
    h[j] = (_Float16)fmaf((float)q, sc, m);
  }
  size_t off = (size_t)g * 64 + (hi ? 0 : 32) + (s & 3) * 8;
  *(half8*)(W + off) = h;
}

// ---------------- pass 3: GEMM C = A @ B^T + bias ----------------
// 256x256 tile, BK=32, 8 waves (2Mx4N, wave tile 128x64), triple-buffered
// 96KB LDS, counted vmcnt(4) (prefetch distance 2 K-tiles), T2 XOR swizzle,
// 2-phase K-tile split (T3-lite) + T5 setprio around each MFMA quadrant.

#define MFMA16(a, b, c) __builtin_amdgcn_mfma_f32_16x16x32_f16((a), (b), (c), 0, 0, 0)

// fused wait+barrier: single asm so nothing slips between drain and barrier
#define WAITBAR4() asm volatile("s_waitcnt vmcnt(4)\n\ts_barrier" ::: "memory")
#define WAITBAR0() asm volatile("s_waitcnt vmcnt(0)\n\ts_barrier" ::: "memory")

// One K-tile: 2 phases. Phase A: stage A(t+2), read Q0 frags, barrier, 16 MFMA.
// Phase B: stage B(t+2), read Q1 A-frags (B reused), barrier, 16 MFMA, WAITBAR4.
__device__ __forceinline__ void tile_body(const _Float16* bA, const _Float16* bB,
                                          const char* ga, const char* gb,
                                          char* lA2, char* lB2,
                                          floatx4 (&acc)[8][4],
                                          int lofs, int arow, int brow, size_t K2) {
  // ---- phase A ----
  gload16(ga,            lA2);
  gload16(ga + 128 * K2, lA2 + 8192);
  half8 af[4], bf[4];
#pragma unroll
  for (int fr = 0; fr < 4; ++fr)
    af[fr] = *(const half8*)(bA + (arow + fr * 16) * 32 + lofs);
#pragma unroll
  for (int fc = 0; fc < 4; ++fc)
    bf[fc] = *(const half8*)(bB + (brow + fc * 16) * 32 + lofs);
  __builtin_amdgcn_s_barrier();
  __builtin_amdgcn_s_setprio(1);
#pragma unroll
  for (int fr = 0; fr < 4; ++fr)
#pragma unroll
    for (int fc = 0; fc < 4; ++fc)
      acc[fr][fc] = MFMA16(af[fr], bf[fc], acc[fr][fc]);
  __builtin_amdgcn_s_setprio(0);
  // ---- phase B ----
  gload16(gb,            lB2);
  gload16(gb + 128 * K2, lB2 + 8192);
  half8 ag[4];
#pragma unroll
  for (int fr = 0; fr < 4; ++fr)
    ag[fr] = *(const half8*)(bA + (arow + 64 + fr * 16) * 32 + lofs);
  __builtin_amdgcn_s_barrier();
  __builtin_amdgcn_s_setprio(1);
#pragma unroll
  for (int fr = 0; fr < 4; ++fr)
#pragma unroll
    for (int fc = 0; fc < 4; ++fc)
      acc[4 + fr][fc] = MFMA16(ag[fr], bf[fc], acc[4 + fr][fc]);
  __builtin_amdgcn_s_setprio(0);
  WAITBAR4();
}

// epilogue compute (no staging)
__device__ __forceinline__ void compute_full(const _Float16* bA, const _Float16* bB,
                                             floatx4 (&acc)[8][4],
                                             int lofs, int arow, int brow) {
  half8 af[8], bf[4];
#pragma unroll
  for (int fr = 0; fr < 8; ++fr)
    af[fr] = *(const half8*)(bA + (arow + fr * 16) * 32 + lofs);
#pragma unroll
  for (int fc = 0; fc < 4; ++fc)
    bf[fc] = *(const half8*)(bB + (brow + fc * 16) * 32 + lofs);
  __builtin_amdgcn_s_setprio(1);
#pragma unroll
  for (int fr = 0; fr < 8; ++fr)
#pragma unroll
    for (int fc = 0; fc < 4; ++fc)
      acc[fr][fc] = MFMA16(af[fr], bf[fc], acc[fr][fc]);
  __builtin_amdgcn_s_setprio(0);
}

__global__ __launch_bounds__(512, 2) void gemm_f16(const _Float16* __restrict__ A,
                                                   const _Float16* __restrict__ B,
                                                   const float* __restrict__ bias,
                                                   float* __restrict__ C) {
  __shared__ __align__(16) _Float16 smem[3 * 16384];   // 96 KiB

  int bid = blockIdx.x;
  int swz = (bid & 7) * (NWG >> 3) + (bid >> 3);   // XCD-aware, bijective
  int tm = swz / NT_N, tn = swz % NT_N;

  int tid  = threadIdx.x;
  int wave = tid >> 6, lane = tid & 63;
  int wm = wave >> 2, wn = wave & 3;       // 2M x 4N waves, wave tile 128x64

  // staging: thread t covers LDS bytes t*16 of each 8KB half (linear dest);
  // source pre-swizzled: k-slot = (t&3) ^ ((t>>3)&3)  (m97/m104 + rule 21)
  const size_t K2 = (size_t)IFEAT * 2;
  int kswz = (((tid & 3) ^ ((tid >> 3) & 3)) << 4);
  const char* gA = (const char*)A + (size_t)(tm * BM + (tid >> 2)) * K2 + kswz;
  const char* gB = (const char*)B + (size_t)(tn * BN + (tid >> 2)) * K2 + kswz;

  int dstoff = wave * 1024;                // wave-uniform LDS dest offset
  _Float16* A0 = smem;              _Float16* B0 = smem + 8192;
  _Float16* A1 = smem + 16384;      _Float16* B1 = smem + 24576;
  _Float16* A2 = smem + 32768;      _Float16* B2 = smem + 40960;
  char* lA0 = (char*)A0 + dstoff;  char* lB0 = (char*)B0 + dstoff;
  char* lA1 = (char*)A1 + dstoff;  char* lB1 = (char*)B1 + dstoff;
  char* lA2 = (char*)A2 + dstoff;  char* lB2 = (char*)B2 + dstoff;

  // fragment read: lane l -> row R+(l&15), physical slot (l>>4)^(((l&15)>>1)&3)
  int x = lane & 15;
  int pslot = (lane >> 4) ^ ((x >> 1) & 3);
  int lofs = x * 32 + pslot * 8;           // f16 units (row stride 32)
  const int arow = wm * 128;
  const int brow = wn * 64;

  floatx4 acc[8][4] = {};

  // prologue: stage tiles 0,1; drain to 4 (tile 0 confirmed)
  gload16(gA,            lA0);  gload16(gA + 128 * K2, lA0 + 8192);
  gload16(gB,            lB0);  gload16(gB + 128 * K2, lB0 + 8192);
  gload16(gA + 64,       lA1);  gload16(gA + 64 + 128 * K2, lA1 + 8192);
  gload16(gB + 64,       lB1);  gload16(gB + 64 + 128 * K2, lB1 + 8192);
  WAITBAR4();

  // main loop: 42 iterations x 3 tiles. Invariant at body entry: tile t
  // confirmed, t+1's 4 loads outstanding. Body stages t+2, computes t,
  // drains to 4 (confirms t+1). Buffer (t+2)%3 sealed since end of t-1.
  for (int t = 0; t < NKT - 2; t += 3) {
    const char* a = gA + (size_t)(t + 2) * 64;
    const char* b = gB + (size_t)(t + 2) * 64;
    tile_body(A0, B0, a,       b,       lA2, lB2, acc, lofs, arow, brow, K2);
    tile_body(A1, B1, a + 64,  b + 64,  lA0, lB0, acc, lofs, arow, brow, K2);
    tile_body(A2, B2, a + 128, b + 128, lA1, lB1, acc, lofs, arow, brow, K2);
  }
  // tiles 126 (buf0, confirmed) and 127 (buf1, in flight)
  compute_full(A0, B0, acc, lofs, arow, brow);
  WAITBAR0();
  compute_full(A1, B1, acc, lofs, arow, brow);

  // epilogue: C/D layout col = lane&15, row = (lane>>4)*4 + reg
  int rowq = (lane >> 4) << 2;
  int colbase = tn * BN + brow + x;
#pragma unroll
  for (int fc = 0; fc < 4; ++fc) {
    int col = colbase + fc * 16;
    float bv = bias[col];
#pragma unroll
    for (int fr = 0; fr < 8; ++fr) {
      int row = tm * BM + arow + fr * 16 + rowq;
#pragma unroll
      for (int p = 0; p < 4; ++p)
        C[(size_t)(row + p) * OFEAT + col] = acc[fr][fc][p] + bv;
    }
  }
}

extern "C" void kernel_launch(void* const* d_in, const int* in_sizes, int n_in,
                              void* d_out, int out_size, void* d_ws, size_t ws_size,
                              hipStream_t stream) {
  const float* x         = (const float*)d_in[0];
  const void*  packed    = d_in[1];
  const float* mn        = (const float*)d_in[2];
  const float* inv_scale = (const float*)d_in[3];
  const float* bias      = (const float*)d_in[4];
  float* out = (float*)d_out;

  _Float16* xh = (_Float16*)d_ws;
  _Float16* wh = (_Float16*)((char*)d_ws + (size_t)TOKENS * IFEAT * 2);

  cvt_x<<<(TOKENS * IFEAT) / (256 * 8), 256, 0, stream>>>(x, xh);
  dequant_w<<<(NGTOT * 8) / 256, 256, 0, stream>>>(packed, mn, inv_scale, wh);
  gemm_f16<<<NWG, 512, 0, stream>>>(xh, wh, bias, out);
}